// Round 3
// baseline (1541.495 us; speedup 1.0000x reference)
//
#include <hip/hip_runtime.h>
#include <hip/hip_bf16.h>

// DIN sequence encoder, B=4096 L=200 E=A=128, fp32 I/O, bf16 MFMA compute.
//
// v6: 1-tile chunks. v4/v5 proved that with a 64-reg accumulator the
// launch_bounds(256,3) cap (~170 unified VGPR+AGPR) always spills
// (WRITE_SIZE 682/461 MB of scratch). v6 cuts the accumulator to acc[8]=32
// regs (one L-tile per chunk, up to 4 chunks/wave):
//   - peak live ~105 regs: acc 32 + bf[8] 32 + af/aq 16 + q 8 + addr ~15
//   - h1buf 4 slots = 17.4 KB -> LDS ~21 KB (not the binder)
//   - 3 (maybe 4) waves/SIMD = 12-16 waves/CU vs v3's 8
//   - bf[8] batch loads restored (8 L2 loads in flight per half)
// Cost: B-frags amortize over 1 tile (more L2 frag traffic, latency-hidden).
// Tail: weighted-sum loop unrolled 4x with independent accumulators
// (acc regs dead there; breaks the ~25-iter serial L2 latency chain).

typedef __attribute__((ext_vector_type(8))) short short8;
typedef __attribute__((ext_vector_type(4))) float f32x4;

__device__ __forceinline__ float bf2f(short s) {
    return __uint_as_float(((unsigned)(unsigned short)s) << 16);
}
__device__ __forceinline__ short f2bf(float f) {
    unsigned u = __float_as_uint(f);
    u = (u + 0x7fff + ((u >> 16) & 1)) >> 16;   // RNE; inputs finite
    return (short)u;
}

// ---- prep 1: fragment-ordered B blocks (bf16) into ws ----------------------
// F1[kb=sp*2+half][n][lane][j] : half0 = Wk = W1b - W1c, half1 = Wqk = W1d
//   value = B[k = 32*sp + 8*(lane>>4) + j][col = n*16 + (lane&15)]
// F2[s2][n][lane][j]           : W2, k = 32*s2 + 8*(lane>>4) + j
__global__ void prep_frag(const float* __restrict__ W1, const float* __restrict__ W2,
                          short* __restrict__ F1, short* __restrict__ F2) {
    int idx = blockIdx.x * 256 + threadIdx.x;   // 6144 threads
    if (idx < 4096) {
        int lane = idx & 63, n = (idx >> 6) & 7, kb = idx >> 9;
        int q = lane >> 4, l15 = lane & 15;
        int sp = kb >> 1, half = kb & 1;
        int col = n * 16 + l15;
        short8 v;
        #pragma unroll
        for (int j = 0; j < 8; ++j) {
            int k = 32 * sp + 8 * q + j;
            float x = half ? W1[(384 + k) * 128 + col]
                           : W1[(128 + k) * 128 + col] - W1[(256 + k) * 128 + col];
            v[j] = f2bf(x);
        }
        *(short8*)(F1 + idx * 8) = v;
    } else if (idx < 6144) {
        int i2 = idx - 4096;
        int lane = i2 & 63, n = (i2 >> 6) & 7, s2 = i2 >> 9;
        int q = lane >> 4, l15 = lane & 15;
        int col = n * 16 + l15;
        short8 v;
        #pragma unroll
        for (int j = 0; j < 8; ++j)
            v[j] = f2bf(W2[(32 * s2 + 8 * q + j) * 128 + col]);
        *(short8*)(F2 + i2 * 8) = v;
    }
}

// ---- prep 2: qW[b][n] = b1[n] + sum_k q[b][k]*(W1a+W1c)[k][n]  (fp32) ------
__global__ void prep_qw(const float* __restrict__ query, const float* __restrict__ W1,
                        const float* __restrict__ b1, float* __restrict__ qw) {
    __shared__ float qsh[128];
    const int b = blockIdx.x, t = threadIdx.x;   // 128 threads
    qsh[t] = query[b * 128 + t];
    __syncthreads();
    float acc = b1[t];
    #pragma unroll 4
    for (int k = 0; k < 128; ++k)
        acc += qsh[k] * (W1[k * 128 + t] + W1[(256 + k) * 128 + t]);
    qw[b * 128 + t] = acc;
}

// ---- main: one workgroup per batch row -------------------------------------
#define HSTR 136  // h1buf row stride in shorts (272 B: 16B-aligned, 2-way-max banks)

__launch_bounds__(256, 3)
__global__ void din_main(const float* __restrict__ query, const float* __restrict__ keys,
                         const int* __restrict__ klen, const float* __restrict__ pos,
                         const float* __restrict__ b2g, const float* __restrict__ w3g,
                         const float* __restrict__ qw, const short* __restrict__ F1,
                         const short* __restrict__ F2, float* __restrict__ out) {
    __shared__ alignas(16) short h1buf[4 * 16 * HSTR];   // 17408 B: 1 slot/wave
    __shared__ float qv[128];
    __shared__ float s_lds[208];
    __shared__ float w_lds[208];
    __shared__ float part[512];
    __shared__ float red[8];

    const int t = threadIdx.x;
    const int b = blockIdx.x;
    const int w = t >> 6;
    const int lane = t & 63;
    const int quad = lane >> 4;
    const int l15 = lane & 15;

    const int len = klen[b];
    const int T = (len + 15) >> 4;                       // tiles actually needed
    const int cnt = (T > w) ? ((T - w + 3) >> 2) : 0;    // this wave's tiles (<=4)

    if (t < 128) qv[t] = query[b * 128 + t];
    __syncthreads();

    // up to 4 chunks of 1 tile each; h1buf slot w is wave-private
    for (int c = 0; c < 4; ++c) {
        if (c >= cnt) break;           // wave-uniform (cnt depends only on w)

        const int tile = w + 4 * c;
        const int row = tile * 16 + l15;

        f32x4 acc[8];
        #pragma unroll
        for (int n = 0; n < 8; ++n) acc[n] = (f32x4){0.f, 0.f, 0.f, 0.f};

        // ---- GEMM1: K=256, A = [kp | kp*q] built from global keys ----
        for (int sp = 0; sp < 4; ++sp) {
            // build kp frag for this tile
            short8 af;
            #pragma unroll
            for (int j = 0; j < 8; ++j) af[j] = 0;
            if (row < 200) {
                const float* kr = keys + ((long)b * 200 + row) * 128 + 32 * sp + 8 * quad;
                const float* pr = pos + (long)row * 128 + 32 * sp + 8 * quad;
                float4 k0 = *(const float4*)kr, k1 = *(const float4*)(kr + 4);
                float4 p0 = *(const float4*)pr, p1 = *(const float4*)(pr + 4);
                af[0] = f2bf(k0.x + p0.x); af[1] = f2bf(k0.y + p0.y);
                af[2] = f2bf(k0.z + p0.z); af[3] = f2bf(k0.w + p0.w);
                af[4] = f2bf(k1.x + p1.x); af[5] = f2bf(k1.y + p1.y);
                af[6] = f2bf(k1.z + p1.z); af[7] = f2bf(k1.w + p1.w);
            }
            // half 0: kp @ Wk, bf[8] batch (8 L2 loads in flight)
            {
                short8 bf[8];
                #pragma unroll
                for (int n = 0; n < 8; ++n)
                    bf[n] = *(const short8*)(F1 + (((2 * sp) * 8 + n) * 64 + lane) * 8);
                #pragma unroll
                for (int n = 0; n < 8; ++n)
                    acc[n] = __builtin_amdgcn_mfma_f32_16x16x32_bf16(af, bf[n], acc[n], 0, 0, 0);
            }
            // half 1: (kp*q) @ Wqk — scale kept kp frag by q, repack
            {
                float4 qa = *(const float4*)(qv + 32 * sp + 8 * quad);
                float4 qb = *(const float4*)(qv + 32 * sp + 8 * quad + 4);
                short8 aq;
                aq[0] = f2bf(bf2f(af[0]) * qa.x); aq[1] = f2bf(bf2f(af[1]) * qa.y);
                aq[2] = f2bf(bf2f(af[2]) * qa.z); aq[3] = f2bf(bf2f(af[3]) * qa.w);
                aq[4] = f2bf(bf2f(af[4]) * qb.x); aq[5] = f2bf(bf2f(af[5]) * qb.y);
                aq[6] = f2bf(bf2f(af[6]) * qb.z); aq[7] = f2bf(bf2f(af[7]) * qb.w);
                short8 bf[8];
                #pragma unroll
                for (int n = 0; n < 8; ++n)
                    bf[n] = *(const short8*)(F1 + (((2 * sp + 1) * 8 + n) * 64 + lane) * 8);
                #pragma unroll
                for (int n = 0; n < 8; ++n)
                    acc[n] = __builtin_amdgcn_mfma_f32_16x16x32_bf16(aq, bf[n], acc[n], 0, 0, 0);
            }
        }

        // ---- h1 = relu(acc + qW) -> LDS slot w (C-layout -> A-layout) ----
        #pragma unroll
        for (int n = 0; n < 8; ++n) {
            float qwn = qw[b * 128 + n * 16 + l15];
            #pragma unroll
            for (int r = 0; r < 4; ++r) {
                float v = acc[n][r] + qwn;
                h1buf[(w * 16 + quad * 4 + r) * HSTR + n * 16 + l15] =
                    f2bf(v > 0.f ? v : 0.f);
            }
        }

        // ---- GEMM2: h1 @ W2 (K=128), B-frags from global F2 ----
        #pragma unroll
        for (int n = 0; n < 8; ++n) acc[n] = (f32x4){0.f, 0.f, 0.f, 0.f};
        for (int s2 = 0; s2 < 4; ++s2) {
            short8 a2 = *(const short8*)(h1buf + (w * 16 + l15) * HSTR + 32 * s2 + 8 * quad);
            short8 bf[8];
            #pragma unroll
            for (int n = 0; n < 8; ++n)
                bf[n] = *(const short8*)(F2 + ((s2 * 8 + n) * 64 + lane) * 8);
            #pragma unroll
            for (int n = 0; n < 8; ++n)
                acc[n] = __builtin_amdgcn_mfma_f32_16x16x32_bf16(a2, bf[n], acc[n], 0, 0, 0);
        }

        // ---- scores: s = sum_n relu(h2 + b2) * W3[n] ----
        {
            float p[4] = {0.f, 0.f, 0.f, 0.f};
            #pragma unroll
            for (int n = 0; n < 8; ++n) {
                float b2n = b2g[n * 16 + l15];
                float w3n = w3g[n * 16 + l15];
                #pragma unroll
                for (int r = 0; r < 4; ++r) {
                    float v = acc[n][r] + b2n;
                    p[r] += (v > 0.f ? v : 0.f) * w3n;
                }
            }
            #pragma unroll
            for (int off = 8; off >= 1; off >>= 1)
                #pragma unroll
                for (int r = 0; r < 4; ++r) p[r] += __shfl_xor(p[r], off, 64);
            if (l15 == 0) {
                #pragma unroll
                for (int r = 0; r < 4; ++r)
                    s_lds[tile * 16 + quad * 4 + r] = p[r];
            }
        }
    }
    __syncthreads();

    // ---- masked softmax over L (b3 dropped: shift-invariant) ----
    float sv = (t < 208 && t < len) ? s_lds[t] : -1e9f;
    float m = sv;
    #pragma unroll
    for (int off = 32; off >= 1; off >>= 1) m = fmaxf(m, __shfl_xor(m, off, 64));
    if (lane == 0) red[w] = m;
    __syncthreads();
    m = fmaxf(fmaxf(red[0], red[1]), fmaxf(red[2], red[3]));
    float e = (t < 208 && t < len) ? expf(sv - m) : 0.f;
    float ssum = e;
    #pragma unroll
    for (int off = 32; off >= 1; off >>= 1) ssum += __shfl_xor(ssum, off, 64);
    if (lane == 0) red[4 + w] = ssum;
    __syncthreads();
    float S = red[4] + red[5] + red[6] + red[7];
    if (t < 208) w_lds[t] = e / S;
    __syncthreads();

    // ---- out[b][e] = sum_{l<len} w[l]*(keys+pos)[l][e]  (keys L2/L3-hot) ----
    // unrolled 4x with independent accumulators: 4 loads in flight per thread
    const int qt = t >> 6;
    const int e2h = t & 63;          // float2 column pair index
    const float2* kr = (const float2*)(keys + (long)b * 200 * 128);
    const float2* pr = (const float2*)pos;
    float ax0 = 0.f, ay0 = 0.f, ax1 = 0.f, ay1 = 0.f;
    float ax2 = 0.f, ay2 = 0.f, ax3 = 0.f, ay3 = 0.f;
    int l = qt;
    for (; l + 12 < len; l += 16) {
        float w0 = w_lds[l], w1 = w_lds[l + 4], w2 = w_lds[l + 8], w3 = w_lds[l + 12];
        float2 k0 = kr[l * 64 + e2h],        p0 = pr[l * 64 + e2h];
        float2 k1 = kr[(l + 4) * 64 + e2h],  p1 = pr[(l + 4) * 64 + e2h];
        float2 k2 = kr[(l + 8) * 64 + e2h],  p2 = pr[(l + 8) * 64 + e2h];
        float2 k3 = kr[(l + 12) * 64 + e2h], p3 = pr[(l + 12) * 64 + e2h];
        ax0 += w0 * (k0.x + p0.x); ay0 += w0 * (k0.y + p0.y);
        ax1 += w1 * (k1.x + p1.x); ay1 += w1 * (k1.y + p1.y);
        ax2 += w2 * (k2.x + p2.x); ay2 += w2 * (k2.y + p2.y);
        ax3 += w3 * (k3.x + p3.x); ay3 += w3 * (k3.y + p3.y);
    }
    for (; l < len; l += 4) {
        float wgt = w_lds[l];
        float2 kv = kr[l * 64 + e2h];
        float2 pv = pr[l * 64 + e2h];
        ax0 += wgt * (kv.x + pv.x);
        ay0 += wgt * (kv.y + pv.y);
    }
    part[qt * 128 + 2 * e2h]     = (ax0 + ax1) + (ax2 + ax3);
    part[qt * 128 + 2 * e2h + 1] = (ay0 + ay1) + (ay2 + ay3);
    __syncthreads();
    if (t < 128) {
        float o = part[t] + part[128 + t] + part[256 + t] + part[384 + t];
        out[b * 128 + t] = o;
    }
}

extern "C" void kernel_launch(void* const* d_in, const int* in_sizes, int n_in,
                              void* d_out, int out_size, void* d_ws, size_t ws_size,
                              hipStream_t stream) {
    const float* query = (const float*)d_in[0];
    const float* keys  = (const float*)d_in[1];
    const int*   klen  = (const int*)  d_in[2];
    const float* pos   = (const float*)d_in[3];
    const float* W1    = (const float*)d_in[4];
    const float* b1    = (const float*)d_in[5];
    const float* W2    = (const float*)d_in[6];
    const float* b2    = (const float*)d_in[7];
    const float* W3    = (const float*)d_in[8];
    // d_in[9] = b3: shift-invariant under softmax, unused.
    float* out = (float*)d_out;

    char* ws = (char*)d_ws;
    float* qw = (float*)ws;                    // 4096*128 fp32 = 2 MiB
    short* F1 = (short*)(ws + 2097152);        // 32768 bf16 = 64 KiB
    short* F2 = (short*)(ws + 2097152 + 65536);// 16384 bf16 = 32 KiB

    prep_frag<<<24,   256, 0, stream>>>(W1, W2, F1, F2);
    prep_qw  <<<4096, 128, 0, stream>>>(query, W1, b1, qw);
    din_main <<<4096, 256, 0, stream>>>(query, keys, klen, pos, b2, W3, qw,
                                        F1, F2, out);
}

// Round 6
// 871.839 us; speedup vs baseline: 1.7681x; 1.7681x over previous
//
#include <hip/hip_runtime.h>
#include <hip/hip_bf16.h>

// DIN sequence encoder, B=4096 L=200 E=A=128, fp32 I/O, bf16 MFMA compute.
//
// v7c: 1-tile chunks + LDS PAD to control the register-allocator budget.
// (Second resubmission: rounds 3-4 benches died to container infra before
//  running; kernel audited — all indices in bounds, all loops bounded, no
//  kernel-side hang mechanism. Code identical to v7b.)
// Model from v3-v6 measurements: the scheduler targets the LDS-derived
// achievable occupancy (clamped below by launch_bounds min-waves) and
// SPILLS to meet it:
//   v3: 74KB LDS -> 2 blocks/CU -> budget 256 -> 240 used, no spill (270us)
//   v4/v5: 39KB -> 4 blocks/CU -> budget 128 < ~148 demand -> 461-682MB scratch
//   v6: 22KB -> ~7 blocks/CU -> budget ~73 < ~116 demand -> 2.5GB scratch
// v7 pads static LDS to ~46.7KB: target exactly 3 blocks/CU -> budget ~170
// >= demand ~115 -> NO spill, 12 waves/CU (1.5x v3's 8) on a latency-bound
// kernel (v3: all pipes <20% busy).
//   - no min-waves hint (launch_bounds(256) only)
//   - 1 L-tile per chunk: acc[8] = 32 AGPR
//   - B-frags in groups of 4 (peak live ~115)
//   - weighted-sum tail unrolled 4x (independent L2 chains)

typedef __attribute__((ext_vector_type(8))) short short8;
typedef __attribute__((ext_vector_type(4))) float f32x4;

__device__ __forceinline__ float bf2f(short s) {
    return __uint_as_float(((unsigned)(unsigned short)s) << 16);
}
__device__ __forceinline__ short f2bf(float f) {
    unsigned u = __float_as_uint(f);
    u = (u + 0x7fff + ((u >> 16) & 1)) >> 16;   // RNE; inputs finite
    return (short)u;
}

// ---- prep 1: fragment-ordered B blocks (bf16) into ws ----------------------
// F1[kb=sp*2+half][n][lane][j] : half0 = Wk = W1b - W1c, half1 = Wqk = W1d
//   value = B[k = 32*sp + 8*(lane>>4) + j][col = n*16 + (lane&15)]
// F2[s2][n][lane][j]           : W2, k = 32*s2 + 8*(lane>>4) + j
__global__ void prep_frag(const float* __restrict__ W1, const float* __restrict__ W2,
                          short* __restrict__ F1, short* __restrict__ F2) {
    int idx = blockIdx.x * 256 + threadIdx.x;   // 6144 threads
    if (idx < 4096) {
        int lane = idx & 63, n = (idx >> 6) & 7, kb = idx >> 9;
        int q = lane >> 4, l15 = lane & 15;
        int sp = kb >> 1, half = kb & 1;
        int col = n * 16 + l15;
        short8 v;
        #pragma unroll
        for (int j = 0; j < 8; ++j) {
            int k = 32 * sp + 8 * q + j;
            float x = half ? W1[(384 + k) * 128 + col]
                           : W1[(128 + k) * 128 + col] - W1[(256 + k) * 128 + col];
            v[j] = f2bf(x);
        }
        *(short8*)(F1 + idx * 8) = v;
    } else if (idx < 6144) {
        int i2 = idx - 4096;
        int lane = i2 & 63, n = (i2 >> 6) & 7, s2 = i2 >> 9;
        int q = lane >> 4, l15 = lane & 15;
        int col = n * 16 + l15;
        short8 v;
        #pragma unroll
        for (int j = 0; j < 8; ++j)
            v[j] = f2bf(W2[(32 * s2 + 8 * q + j) * 128 + col]);
        *(short8*)(F2 + i2 * 8) = v;
    }
}

// ---- prep 2: qW[b][n] = b1[n] + sum_k q[b][k]*(W1a+W1c)[k][n]  (fp32) ------
__global__ void prep_qw(const float* __restrict__ query, const float* __restrict__ W1,
                        const float* __restrict__ b1, float* __restrict__ qw) {
    __shared__ float qsh[128];
    const int b = blockIdx.x, t = threadIdx.x;   // 128 threads
    qsh[t] = query[b * 128 + t];
    __syncthreads();
    float acc = b1[t];
    #pragma unroll 4
    for (int k = 0; k < 128; ++k)
        acc += qsh[k] * (W1[k * 128 + t] + W1[(256 + k) * 128 + t]);
    qw[b * 128 + t] = acc;
}

// ---- main: one workgroup per batch row -------------------------------------
#define HSTR 136  // h1buf row stride in shorts (272 B: 16B-aligned, 2-way-max banks)

__launch_bounds__(256)
__global__ void din_main(const float* __restrict__ query, const float* __restrict__ keys,
                         const int* __restrict__ klen, const float* __restrict__ pos,
                         const float* __restrict__ b2g, const float* __restrict__ w3g,
                         const float* __restrict__ qw, const short* __restrict__ F1,
                         const short* __restrict__ F2, float* __restrict__ out) {
    __shared__ alignas(16) short h1buf[4 * 16 * HSTR];   // 17408 B: 1 slot/wave
    __shared__ float qv[128];
    __shared__ float s_lds[208];
    __shared__ float w_lds[208];
    __shared__ float part[512];
    __shared__ float red[8];
    // Occupancy governor: pad static LDS into the (40, 53.3] KB window so the
    // compiler's LDS-derived occupancy target is 3 blocks/CU -> RA budget ~170
    // regs/wave -> no spill-to-meet-occupancy (the v4-v6 failure mode).
    __shared__ float pad_lds[6250];                      // 25000 B

    const int t = threadIdx.x;
    const int b = blockIdx.x;
    const int w = t >> 6;
    const int lane = t & 63;
    const int quad = lane >> 4;
    const int l15 = lane & 15;

    const int len = klen[b];

    // Keep pad_lds allocated: len >= 1 at runtime so this never executes, but
    // the compiler cannot prove it, so pad_lds stays referenced -> allocated.
    if (len == -12345) {
        pad_lds[t] = (float)t;
        __syncthreads();
        out[t] = pad_lds[255 - t];
    }

    const int T = (len + 15) >> 4;                       // tiles actually needed
    const int cnt = (T > w) ? ((T - w + 3) >> 2) : 0;    // this wave's tiles (<=4)

    if (t < 128) qv[t] = query[b * 128 + t];
    __syncthreads();

    // up to 4 chunks of 1 tile each; h1buf slot w is wave-private
    for (int c = 0; c < 4; ++c) {
        if (c >= cnt) break;           // wave-uniform (cnt depends only on w)

        const int tile = w + 4 * c;
        const int row = tile * 16 + l15;

        f32x4 acc[8];
        #pragma unroll
        for (int n = 0; n < 8; ++n) acc[n] = (f32x4){0.f, 0.f, 0.f, 0.f};

        // ---- GEMM1: K=256, A = [kp | kp*q] built from global keys ----
        for (int sp = 0; sp < 4; ++sp) {
            // build kp frag for this tile
            short8 af;
            #pragma unroll
            for (int j = 0; j < 8; ++j) af[j] = 0;
            if (row < 200) {
                const float* kr = keys + ((long)b * 200 + row) * 128 + 32 * sp + 8 * quad;
                const float* pr = pos + (long)row * 128 + 32 * sp + 8 * quad;
                float4 k0 = *(const float4*)kr, k1 = *(const float4*)(kr + 4);
                float4 p0 = *(const float4*)pr, p1 = *(const float4*)(pr + 4);
                af[0] = f2bf(k0.x + p0.x); af[1] = f2bf(k0.y + p0.y);
                af[2] = f2bf(k0.z + p0.z); af[3] = f2bf(k0.w + p0.w);
                af[4] = f2bf(k1.x + p1.x); af[5] = f2bf(k1.y + p1.y);
                af[6] = f2bf(k1.z + p1.z); af[7] = f2bf(k1.w + p1.w);
            }
            // half 0: kp @ Wk, B-frags in groups of 4
            #pragma unroll
            for (int g = 0; g < 2; ++g) {
                short8 bf[4];
                #pragma unroll
                for (int n = 0; n < 4; ++n)
                    bf[n] = *(const short8*)(F1 + (((2 * sp) * 8 + g * 4 + n) * 64 + lane) * 8);
                #pragma unroll
                for (int n = 0; n < 4; ++n)
                    acc[g * 4 + n] = __builtin_amdgcn_mfma_f32_16x16x32_bf16(af, bf[n], acc[g * 4 + n], 0, 0, 0);
            }
            // half 1: (kp*q) @ Wqk — scale kept kp frag by q, repack
            {
                float4 qa = *(const float4*)(qv + 32 * sp + 8 * quad);
                float4 qb = *(const float4*)(qv + 32 * sp + 8 * quad + 4);
                short8 aq;
                aq[0] = f2bf(bf2f(af[0]) * qa.x); aq[1] = f2bf(bf2f(af[1]) * qa.y);
                aq[2] = f2bf(bf2f(af[2]) * qa.z); aq[3] = f2bf(bf2f(af[3]) * qa.w);
                aq[4] = f2bf(bf2f(af[4]) * qb.x); aq[5] = f2bf(bf2f(af[5]) * qb.y);
                aq[6] = f2bf(bf2f(af[6]) * qb.z); aq[7] = f2bf(bf2f(af[7]) * qb.w);
                #pragma unroll
                for (int g = 0; g < 2; ++g) {
                    short8 bf[4];
                    #pragma unroll
                    for (int n = 0; n < 4; ++n)
                        bf[n] = *(const short8*)(F1 + (((2 * sp + 1) * 8 + g * 4 + n) * 64 + lane) * 8);
                    #pragma unroll
                    for (int n = 0; n < 4; ++n)
                        acc[g * 4 + n] = __builtin_amdgcn_mfma_f32_16x16x32_bf16(aq, bf[n], acc[g * 4 + n], 0, 0, 0);
                }
            }
        }

        // ---- h1 = relu(acc + qW) -> LDS slot w (C-layout -> A-layout) ----
        #pragma unroll
        for (int n = 0; n < 8; ++n) {
            float qwn = qw[b * 128 + n * 16 + l15];
            #pragma unroll
            for (int r = 0; r < 4; ++r) {
                float v = acc[n][r] + qwn;
                h1buf[(w * 16 + quad * 4 + r) * HSTR + n * 16 + l15] =
                    f2bf(v > 0.f ? v : 0.f);
            }
        }

        // ---- GEMM2: h1 @ W2 (K=128), B-frags from global F2 ----
        #pragma unroll
        for (int n = 0; n < 8; ++n) acc[n] = (f32x4){0.f, 0.f, 0.f, 0.f};
        for (int s2 = 0; s2 < 4; ++s2) {
            short8 a2 = *(const short8*)(h1buf + (w * 16 + l15) * HSTR + 32 * s2 + 8 * quad);
            #pragma unroll
            for (int g = 0; g < 2; ++g) {
                short8 bf[4];
                #pragma unroll
                for (int n = 0; n < 4; ++n)
                    bf[n] = *(const short8*)(F2 + ((s2 * 8 + g * 4 + n) * 64 + lane) * 8);
                #pragma unroll
                for (int n = 0; n < 4; ++n)
                    acc[g * 4 + n] = __builtin_amdgcn_mfma_f32_16x16x32_bf16(a2, bf[n], acc[g * 4 + n], 0, 0, 0);
            }
        }

        // ---- scores: s = sum_n relu(h2 + b2) * W3[n] ----
        {
            float p[4] = {0.f, 0.f, 0.f, 0.f};
            #pragma unroll
            for (int n = 0; n < 8; ++n) {
                float b2n = b2g[n * 16 + l15];
                float w3n = w3g[n * 16 + l15];
                #pragma unroll
                for (int r = 0; r < 4; ++r) {
                    float v = acc[n][r] + b2n;
                    p[r] += (v > 0.f ? v : 0.f) * w3n;
                }
            }
            #pragma unroll
            for (int off = 8; off >= 1; off >>= 1)
                #pragma unroll
                for (int r = 0; r < 4; ++r) p[r] += __shfl_xor(p[r], off, 64);
            if (l15 == 0) {
                #pragma unroll
                for (int r = 0; r < 4; ++r)
                    s_lds[tile * 16 + quad * 4 + r] = p[r];
            }
        }
    }
    __syncthreads();

    // ---- masked softmax over L (b3 dropped: shift-invariant) ----
    float sv = (t < 208 && t < len) ? s_lds[t] : -1e9f;
    float m = sv;
    #pragma unroll
    for (int off = 32; off >= 1; off >>= 1) m = fmaxf(m, __shfl_xor(m, off, 64));
    if (lane == 0) red[w] = m;
    __syncthreads();
    m = fmaxf(fmaxf(red[0], red[1]), fmaxf(red[2], red[3]));
    float e = (t < 208 && t < len) ? expf(sv - m) : 0.f;
    float ssum = e;
    #pragma unroll
    for (int off = 32; off >= 1; off >>= 1) ssum += __shfl_xor(ssum, off, 64);
    if (lane == 0) red[4 + w] = ssum;
    __syncthreads();
    float S = red[4] + red[5] + red[6] + red[7];
    if (t < 208) w_lds[t] = e / S;
    __syncthreads();

    // ---- out[b][e] = sum_{l<len} w[l]*(keys+pos)[l][e]  (keys L2/L3-hot) ----
    // unrolled 4x with independent accumulators: 4 loads in flight per thread
    const int qt = t >> 6;
    const int e2h = t & 63;          // float2 column pair index
    const float2* kr = (const float2*)(keys + (long)b * 200 * 128);
    const float2* pr = (const float2*)pos;
    float ax0 = 0.f, ay0 = 0.f, ax1 = 0.f, ay1 = 0.f;
    float ax2 = 0.f, ay2 = 0.f, ax3 = 0.f, ay3 = 0.f;
    int l = qt;
    for (; l + 12 < len; l += 16) {
        float w0 = w_lds[l], w1 = w_lds[l + 4], w2 = w_lds[l + 8], w3 = w_lds[l + 12];
        float2 k0 = kr[l * 64 + e2h],        p0 = pr[l * 64 + e2h];
        float2 k1 = kr[(l + 4) * 64 + e2h],  p1 = pr[(l + 4) * 64 + e2h];
        float2 k2 = kr[(l + 8) * 64 + e2h],  p2 = pr[(l + 8) * 64 + e2h];
        float2 k3 = kr[(l + 12) * 64 + e2h], p3 = pr[(l + 12) * 64 + e2h];
        ax0 += w0 * (k0.x + p0.x); ay0 += w0 * (k0.y + p0.y);
        ax1 += w1 * (k1.x + p1.x); ay1 += w1 * (k1.y + p1.y);
        ax2 += w2 * (k2.x + p2.x); ay2 += w2 * (k2.y + p2.y);
        ax3 += w3 * (k3.x + p3.x); ay3 += w3 * (k3.y + p3.y);
    }
    for (; l < len; l += 4) {
        float wgt = w_lds[l];
        float2 kv = kr[l * 64 + e2h];
        float2 pv = pr[l * 64 + e2h];
        ax0 += wgt * (kv.x + pv.x);
        ay0 += wgt * (kv.y + pv.y);
    }
    part[qt * 128 + 2 * e2h]     = (ax0 + ax1) + (ax2 + ax3);
    part[qt * 128 + 2 * e2h + 1] = (ay0 + ay1) + (ay2 + ay3);
    __syncthreads();
    if (t < 128) {
        float o = part[t] + part[128 + t] + part[256 + t] + part[384 + t];
        out[b * 128 + t] = o;
    }
}

extern "C" void kernel_launch(void* const* d_in, const int* in_sizes, int n_in,
                              void* d_out, int out_size, void* d_ws, size_t ws_size,
                              hipStream_t stream) {
    const float* query = (const float*)d_in[0];
    const float* keys  = (const float*)d_in[1];
    const int*   klen  = (const int*)  d_in[2];
    const float* pos   = (const float*)d_in[3];
    const float* W1    = (const float*)d_in[4];
    const float* b1    = (const float*)d_in[5];
    const float* W2    = (const float*)d_in[6];
    const float* b2    = (const float*)d_in[7];
    const float* W3    = (const float*)d_in[8];
    // d_in[9] = b3: shift-invariant under softmax, unused.
    float* out = (float*)d_out;

    char* ws = (char*)d_ws;
    float* qw = (float*)ws;                    // 4096*128 fp32 = 2 MiB
    short* F1 = (short*)(ws + 2097152);        // 32768 bf16 = 64 KiB
    short* F2 = (short*)(ws + 2097152 + 65536);// 16384 bf16 = 32 KiB

    prep_frag<<<24,   256, 0, stream>>>(W1, W2, F1, F2);
    prep_qw  <<<4096, 128, 0, stream>>>(query, W1, b1, qw);
    din_main <<<4096, 256, 0, stream>>>(query, keys, klen, pos, b2, W3, qw,
                                        F1, F2, out);
}

// Round 7
// 678.173 us; speedup vs baseline: 2.2730x; 1.2856x over previous
//
#include <hip/hip_runtime.h>
#include <hip/hip_bf16.h>

// DIN sequence encoder, B=4096 L=200 E=A=128, fp32 I/O, bf16 MFMA compute.
//
// v8: REVERT to v3's exact no-spill structure (launch_bounds(256,2), 74KB LDS,
// acc[4][8], 4-tile waves — the only measured config with WRITE_SIZE ~= 2MB),
// then shorten the critical path:
//  1. all hot-path f32->bf16 packing via v_cvt_pk_bf16_f32 (1 VALU op per
//     2 values, RNE — identical rounding to the old manual f2bf). Pack VALU
//     on the load->pack->MFMA chain drops ~4x (VALU was the largest busy
//     component: 15% vs MFMA 6.4%).
//  2. weighted-sum tail unrolled 4x with independent accumulators (breaks the
//     ~25-iteration serial L2-latency chain; acc regs are dead there).
// Occupancy knobs are NOT touched (v4-v7 showed the RA spills or degrades
// under every LDS/launch-bounds variation).

typedef __attribute__((ext_vector_type(8))) short short8;
typedef __attribute__((ext_vector_type(4))) float f32x4;

union frag_u { short8 s; unsigned u[4]; };

__device__ __forceinline__ float bf2f(short s) {
    return __uint_as_float(((unsigned)(unsigned short)s) << 16);
}
__device__ __forceinline__ short f2bf(float f) {          // cold paths only
    unsigned u = __float_as_uint(f);
    u = (u + 0x7fff + ((u >> 16) & 1)) >> 16;   // RNE; inputs finite
    return (short)u;
}
// hot path: 2 floats -> packed 2xbf16 (lo=a, hi=b), single VALU op, RNE
__device__ __forceinline__ unsigned cvt_pk_bf16(float a, float b) {
    unsigned r;
    asm("v_cvt_pk_bf16_f32 %0, %1, %2" : "=v"(r) : "v"(a), "v"(b));
    return r;
}

// ---- prep 1: fragment-ordered B blocks (bf16) into ws ----------------------
// F1[kb=sp*2+half][n][lane][j] : half0 = Wk = W1b - W1c, half1 = Wqk = W1d
//   value = B[k = 32*sp + 8*(lane>>4) + j][col = n*16 + (lane&15)]
// F2[s2][n][lane][j]           : W2, k = 32*s2 + 8*(lane>>4) + j
__global__ void prep_frag(const float* __restrict__ W1, const float* __restrict__ W2,
                          short* __restrict__ F1, short* __restrict__ F2) {
    int idx = blockIdx.x * 256 + threadIdx.x;   // 6144 threads
    if (idx < 4096) {
        int lane = idx & 63, n = (idx >> 6) & 7, kb = idx >> 9;
        int q = lane >> 4, l15 = lane & 15;
        int sp = kb >> 1, half = kb & 1;
        int col = n * 16 + l15;
        short8 v;
        #pragma unroll
        for (int j = 0; j < 8; ++j) {
            int k = 32 * sp + 8 * q + j;
            float x = half ? W1[(384 + k) * 128 + col]
                           : W1[(128 + k) * 128 + col] - W1[(256 + k) * 128 + col];
            v[j] = f2bf(x);
        }
        *(short8*)(F1 + idx * 8) = v;
    } else if (idx < 6144) {
        int i2 = idx - 4096;
        int lane = i2 & 63, n = (i2 >> 6) & 7, s2 = i2 >> 9;
        int q = lane >> 4, l15 = lane & 15;
        int col = n * 16 + l15;
        short8 v;
        #pragma unroll
        for (int j = 0; j < 8; ++j)
            v[j] = f2bf(W2[(32 * s2 + 8 * q + j) * 128 + col]);
        *(short8*)(F2 + i2 * 8) = v;
    }
}

// ---- prep 2: qW[b][n] = b1[n] + sum_k q[b][k]*(W1a+W1c)[k][n]  (fp32) ------
__global__ void prep_qw(const float* __restrict__ query, const float* __restrict__ W1,
                        const float* __restrict__ b1, float* __restrict__ qw) {
    __shared__ float qsh[128];
    const int b = blockIdx.x, t = threadIdx.x;   // 128 threads
    qsh[t] = query[b * 128 + t];
    __syncthreads();
    float acc = b1[t];
    #pragma unroll 4
    for (int k = 0; k < 128; ++k)
        acc += qsh[k] * (W1[k * 128 + t] + W1[(256 + k) * 128 + t]);
    qw[b * 128 + t] = acc;
}

// ---- main: one workgroup per batch row -------------------------------------
#define HSTR 136  // h1buf row stride in shorts

__launch_bounds__(256, 2)
__global__ void din_main(const float* __restrict__ query, const float* __restrict__ keys,
                         const int* __restrict__ klen, const float* __restrict__ pos,
                         const float* __restrict__ b2g, const float* __restrict__ w3g,
                         const float* __restrict__ qw, const short* __restrict__ F1,
                         const short* __restrict__ F2, float* __restrict__ out) {
    __shared__ alignas(16) short h1buf[16 * 16 * HSTR];  // 69632 B
    __shared__ float qv[128];
    __shared__ float s_lds[208];
    __shared__ float w_lds[208];
    __shared__ float part[512];
    __shared__ float red[8];

    const int t = threadIdx.x;
    const int b = blockIdx.x;
    const int w = t >> 6;
    const int lane = t & 63;
    const int quad = lane >> 4;
    const int l15 = lane & 15;

    const int len = klen[b];
    const int T = (len + 15) >> 4;                       // tiles actually needed
    const int cnt = (T > w) ? ((T - w + 3) >> 2) : 0;    // this wave's tiles (<=4)

    if (t < 128) qv[t] = query[b * 128 + t];
    __syncthreads();

    f32x4 acc[4][8];
    #pragma unroll
    for (int i = 0; i < 4; ++i)
        #pragma unroll
        for (int n = 0; n < 8; ++n) acc[i][n] = (f32x4){0.f, 0.f, 0.f, 0.f};

    if (cnt > 0) {
        // ---- GEMM1: K=256, A = [kp | kp*q] built from global keys ----
        for (int sp = 0; sp < 4; ++sp) {
            float4 qa = *(const float4*)(qv + 32 * sp + 8 * quad);
            float4 qb = *(const float4*)(qv + 32 * sp + 8 * quad + 4);
            // half 0: kp
            short8 bf[8];
            #pragma unroll
            for (int n = 0; n < 8; ++n)
                bf[n] = *(const short8*)(F1 + (((2 * sp) * 8 + n) * 64 + lane) * 8);
            short8 af[4];
            #pragma unroll
            for (int i = 0; i < 4; ++i) {
                if (i < cnt) {
                    int row = (w + 4 * i) * 16 + l15;
                    frag_u fu;
                    if (row < 200) {
                        const float* kr = keys + ((long)b * 200 + row) * 128 + 32 * sp + 8 * quad;
                        const float* pr = pos + (long)row * 128 + 32 * sp + 8 * quad;
                        float4 k0 = *(const float4*)kr, k1 = *(const float4*)(kr + 4);
                        float4 p0 = *(const float4*)pr, p1 = *(const float4*)(pr + 4);
                        fu.u[0] = cvt_pk_bf16(k0.x + p0.x, k0.y + p0.y);
                        fu.u[1] = cvt_pk_bf16(k0.z + p0.z, k0.w + p0.w);
                        fu.u[2] = cvt_pk_bf16(k1.x + p1.x, k1.y + p1.y);
                        fu.u[3] = cvt_pk_bf16(k1.z + p1.z, k1.w + p1.w);
                    } else {
                        fu.u[0] = 0; fu.u[1] = 0; fu.u[2] = 0; fu.u[3] = 0;
                    }
                    af[i] = fu.s;
                    #pragma unroll
                    for (int n = 0; n < 8; ++n)
                        acc[i][n] = __builtin_amdgcn_mfma_f32_16x16x32_bf16(af[i], bf[n], acc[i][n], 0, 0, 0);
                }
            }
            // half 1: kp * q  (unpack kept kp-frag, scale by q, repack packed)
            #pragma unroll
            for (int n = 0; n < 8; ++n)
                bf[n] = *(const short8*)(F1 + (((2 * sp + 1) * 8 + n) * 64 + lane) * 8);
            #pragma unroll
            for (int i = 0; i < 4; ++i) {
                if (i < cnt) {
                    frag_u fq;
                    fq.u[0] = cvt_pk_bf16(bf2f(af[i][0]) * qa.x, bf2f(af[i][1]) * qa.y);
                    fq.u[1] = cvt_pk_bf16(bf2f(af[i][2]) * qa.z, bf2f(af[i][3]) * qa.w);
                    fq.u[2] = cvt_pk_bf16(bf2f(af[i][4]) * qb.x, bf2f(af[i][5]) * qb.y);
                    fq.u[3] = cvt_pk_bf16(bf2f(af[i][6]) * qb.z, bf2f(af[i][7]) * qb.w);
                    #pragma unroll
                    for (int n = 0; n < 8; ++n)
                        acc[i][n] = __builtin_amdgcn_mfma_f32_16x16x32_bf16(fq.s, bf[n], acc[i][n], 0, 0, 0);
                }
            }
        }

        // ---- h1 = relu(acc + qW) -> LDS (C-layout -> A-layout), same wave ----
        {
            float qwn[8];
            #pragma unroll
            for (int n = 0; n < 8; ++n) qwn[n] = qw[b * 128 + n * 16 + l15];
            #pragma unroll
            for (int i = 0; i < 4; ++i) {
                if (i < cnt) {
                    #pragma unroll
                    for (int n = 0; n < 8; ++n) {
                        float v0 = fmaxf(acc[i][n][0] + qwn[n], 0.f);
                        float v1 = fmaxf(acc[i][n][1] + qwn[n], 0.f);
                        float v2 = fmaxf(acc[i][n][2] + qwn[n], 0.f);
                        float v3 = fmaxf(acc[i][n][3] + qwn[n], 0.f);
                        unsigned p01 = cvt_pk_bf16(v0, v1);
                        unsigned p23 = cvt_pk_bf16(v2, v3);
                        int base = ((w * 4 + i) * 16 + quad * 4) * HSTR + n * 16 + l15;
                        h1buf[base]            = (short)(p01 & 0xffff);
                        h1buf[base + HSTR]     = (short)(p01 >> 16);
                        h1buf[base + 2 * HSTR] = (short)(p23 & 0xffff);
                        h1buf[base + 3 * HSTR] = (short)(p23 >> 16);
                    }
                }
            }
        }

        // ---- GEMM2: h1 @ W2 (K=128), B-frags from global F2 ----
        #pragma unroll
        for (int i = 0; i < 4; ++i)
            #pragma unroll
            for (int n = 0; n < 8; ++n) acc[i][n] = (f32x4){0.f, 0.f, 0.f, 0.f};
        for (int s2 = 0; s2 < 4; ++s2) {
            short8 bf[8];
            #pragma unroll
            for (int n = 0; n < 8; ++n)
                bf[n] = *(const short8*)(F2 + ((s2 * 8 + n) * 64 + lane) * 8);
            #pragma unroll
            for (int i = 0; i < 4; ++i) {
                if (i < cnt) {
                    short8 a = *(const short8*)(h1buf + ((w * 4 + i) * 16 + l15) * HSTR + 32 * s2 + 8 * quad);
                    #pragma unroll
                    for (int n = 0; n < 8; ++n)
                        acc[i][n] = __builtin_amdgcn_mfma_f32_16x16x32_bf16(a, bf[n], acc[i][n], 0, 0, 0);
                }
            }
        }

        // ---- scores: s = sum_n relu(h2 + b2) * W3[n] ----
        {
            float b2n[8], w3n[8];
            #pragma unroll
            for (int n = 0; n < 8; ++n) {
                b2n[n] = b2g[n * 16 + l15];
                w3n[n] = w3g[n * 16 + l15];
            }
            #pragma unroll
            for (int i = 0; i < 4; ++i) {
                if (i < cnt) {
                    float p[4] = {0.f, 0.f, 0.f, 0.f};
                    #pragma unroll
                    for (int n = 0; n < 8; ++n)
                        #pragma unroll
                        for (int r = 0; r < 4; ++r) {
                            float v = acc[i][n][r] + b2n[n];
                            p[r] += (v > 0.f ? v : 0.f) * w3n[n];
                        }
                    #pragma unroll
                    for (int off = 8; off >= 1; off >>= 1)
                        #pragma unroll
                        for (int r = 0; r < 4; ++r) p[r] += __shfl_xor(p[r], off, 64);
                    if (l15 == 0) {
                        #pragma unroll
                        for (int r = 0; r < 4; ++r)
                            s_lds[(w + 4 * i) * 16 + quad * 4 + r] = p[r];
                    }
                }
            }
        }
    }
    __syncthreads();

    // ---- masked softmax over L (b3 dropped: shift-invariant) ----
    float sv = (t < 208 && t < len) ? s_lds[t] : -1e9f;
    float m = sv;
    #pragma unroll
    for (int off = 32; off >= 1; off >>= 1) m = fmaxf(m, __shfl_xor(m, off, 64));
    if (lane == 0) red[w] = m;
    __syncthreads();
    m = fmaxf(fmaxf(red[0], red[1]), fmaxf(red[2], red[3]));
    float e = (t < 208 && t < len) ? expf(sv - m) : 0.f;
    float ssum = e;
    #pragma unroll
    for (int off = 32; off >= 1; off >>= 1) ssum += __shfl_xor(ssum, off, 64);
    if (lane == 0) red[4 + w] = ssum;
    __syncthreads();
    float S = red[4] + red[5] + red[6] + red[7];
    if (t < 208) w_lds[t] = e / S;
    __syncthreads();

    // ---- out[b][e] = sum_{l<len} w[l]*(keys+pos)[l][e]  (keys L2/L3-hot) ----
    // unrolled 4x with independent accumulators: 4 load pairs in flight
    const int qt = t >> 6;
    const int e2h = t & 63;          // float2 column pair index
    const float2* kr = (const float2*)(keys + (long)b * 200 * 128);
    const float2* pr = (const float2*)pos;
    float ax0 = 0.f, ay0 = 0.f, ax1 = 0.f, ay1 = 0.f;
    float ax2 = 0.f, ay2 = 0.f, ax3 = 0.f, ay3 = 0.f;
    int l = qt;
    for (; l + 12 < len; l += 16) {
        float w0 = w_lds[l], w1 = w_lds[l + 4], w2 = w_lds[l + 8], w3 = w_lds[l + 12];
        float2 k0 = kr[l * 64 + e2h],        p0 = pr[l * 64 + e2h];
        float2 k1 = kr[(l + 4) * 64 + e2h],  p1 = pr[(l + 4) * 64 + e2h];
        float2 k2 = kr[(l + 8) * 64 + e2h],  p2 = pr[(l + 8) * 64 + e2h];
        float2 k3 = kr[(l + 12) * 64 + e2h], p3 = pr[(l + 12) * 64 + e2h];
        ax0 += w0 * (k0.x + p0.x); ay0 += w0 * (k0.y + p0.y);
        ax1 += w1 * (k1.x + p1.x); ay1 += w1 * (k1.y + p1.y);
        ax2 += w2 * (k2.x + p2.x); ay2 += w2 * (k2.y + p2.y);
        ax3 += w3 * (k3.x + p3.x); ay3 += w3 * (k3.y + p3.y);
    }
    for (; l < len; l += 4) {
        float wgt = w_lds[l];
        float2 kv = kr[l * 64 + e2h];
        float2 pv = pr[l * 64 + e2h];
        ax0 += wgt * (kv.x + pv.x);
        ay0 += wgt * (kv.y + pv.y);
    }
    part[qt * 128 + 2 * e2h]     = (ax0 + ax1) + (ax2 + ax3);
    part[qt * 128 + 2 * e2h + 1] = (ay0 + ay1) + (ay2 + ay3);
    __syncthreads();
    if (t < 128) {
        float o = part[t] + part[128 + t] + part[256 + t] + part[384 + t];
        out[b * 128 + t] = o;
    }
}

extern "C" void kernel_launch(void* const* d_in, const int* in_sizes, int n_in,
                              void* d_out, int out_size, void* d_ws, size_t ws_size,
                              hipStream_t stream) {
    const float* query = (const float*)d_in[0];
    const float* keys  = (const float*)d_in[1];
    const int*   klen  = (const int*)  d_in[2];
    const float* pos   = (const float*)d_in[3];
    const float* W1    = (const float*)d_in[4];
    const float* b1    = (const float*)d_in[5];
    const float* W2    = (const float*)d_in[6];
    const float* b2    = (const float*)d_in[7];
    const float* W3    = (const float*)d_in[8];
    // d_in[9] = b3: shift-invariant under softmax, unused.
    float* out = (float*)d_out;

    char* ws = (char*)d_ws;
    float* qw = (float*)ws;                    // 4096*128 fp32 = 2 MiB
    short* F1 = (short*)(ws + 2097152);        // 32768 bf16 = 64 KiB
    short* F2 = (short*)(ws + 2097152 + 65536);// 16384 bf16 = 32 KiB

    prep_frag<<<24,   256, 0, stream>>>(W1, W2, F1, F2);
    prep_qw  <<<4096, 128, 0, stream>>>(query, W1, b1, qw);
    din_main <<<4096, 256, 0, stream>>>(query, keys, klen, pos, b2, W3, qw,
                                        F1, F2, out);
}